// Round 5
// baseline (6736.549 us; speedup 1.0000x reference)
//
#include <hip/hip_runtime.h>
#include <hip/hip_bf16.h>

#define DD 32
#define CC 128
#define N1 1024   // 2*H
#define ROWS 4
#define NBLK 512
#define THREADS 512

#define FRAGS_PER_WAVE 140   // 8 L1 + 128 L2 + 4 L3
#define RING 7               // slots/wave; 7|140; B=2, D=5 -> distances 2..6 mod 7, never 0

typedef float f32x4 __attribute__((ext_vector_type(4)));
typedef __bf16 bf16x8 __attribute__((ext_vector_type(8)));
typedef unsigned short u16x4 __attribute__((ext_vector_type(4)));

#define W1C_OFF 0
#define W1C_SZ (256*1024)
#define STREAM_OFF W1C_SZ
#define STREAM_SZ (1120*1024)   // one copy: 1120 frags x 1 KB

static __device__ __forceinline__ unsigned short f2bfu(float f) {
    __hip_bfloat16 h = __float2bfloat16(f);
    unsigned short u; __builtin_memcpy(&u, &h, 2); return u;
}
static __device__ __forceinline__ float bfu2f(unsigned short u) {
    unsigned int x = ((unsigned int)u) << 16;
    float f; __builtin_memcpy(&f, &x, 4); return f;
}

// 4-row fragment-linear h-buffer index (ushorts) for GLU D-reg writes.
// n_global = nt*16 + q*4 + i (q = lane>>4); addr = (nt>>1)*128 + kgrp*32 + row*8 + (q&1)*4
static __device__ __forceinline__ int h4_idx(int nt, int lane) {
    int q = lane >> 4, row = lane & 15;
    int kgrp = (nt & 1) * 2 + (q >> 1);
    return (nt >> 1) * 128 + kgrp * 32 + row * 8 + (q & 1) * 4;
}

// old-style pack (used for w1c): frag = nt*4 + kt
__global__ void pack_kernel(const float* __restrict__ W, __bf16* __restrict__ dst,
                            int Kreal, int N, int KT) {
    int frag = blockIdx.x;
    int lane = threadIdx.x;
    int nt = frag / KT, kt = frag - nt * KT;
    int kbase = kt * 32 + (lane >> 4) * 8;
    int n = nt * 16 + (lane & 15);
    union { unsigned short b[8]; int4 v; } u;
#pragma unroll
    for (int j = 0; j < 8; j++) {
        int k = kbase + j;
        float v = (k < Kreal) ? W[(size_t)k * N + n] : 0.f;
        u.b[j] = f2bfu(v);
    }
    *reinterpret_cast<int4*>((unsigned short*)dst + (size_t)frag * 512 + lane * 8) = u.v;
}

// per-wave consumption-order stream pack, replicated ncopy times
__global__ void pack_stream(const float* __restrict__ W1, const float* __restrict__ W2,
                            const float* __restrict__ W3, __bf16* __restrict__ dst) {
    int copy = blockIdx.x / 1120;
    int g = blockIdx.x % 1120;
    int lane = threadIdx.x;
    int wv = g / FRAGS_PER_WAVE, seq = g % FRAGS_PER_WAVE;
    const float* W; int Kreal, N, kt, nt;
    if (seq < 8) {             // L1: theta rows of W1 (K=32)
        int p = seq >> 1, ab = seq & 1;
        W = W1; Kreal = 32; N = N1; kt = 0;
        nt = wv * 4 + p + 32 * ab;
    } else if (seq < 136) {    // L2: kt-major, (p,ab)-minor
        int s = seq - 8;
        int ktt = s >> 3, j = s & 7, p = j >> 1, ab = j & 1;
        W = W2; Kreal = 512; N = N1;
        kt = ktt; nt = wv * 4 + p + 32 * ab;
    } else {                   // L3: wave -> (nt3 = wv&1, kq = wv>>1), kt = kq*4 + q
        int q = seq - 136;
        W = W3; Kreal = 512; N = DD;
        kt = (wv >> 1) * 4 + q; nt = wv & 1;
    }
    int kbase = kt * 32 + (lane >> 4) * 8;
    int n = nt * 16 + (lane & 15);
    union { unsigned short b[8]; int4 v; } u;
#pragma unroll
    for (int j = 0; j < 8; j++) {
        int k = kbase + j;
        float v = (k < Kreal) ? W[(size_t)k * N + n] : 0.f;
        u.b[j] = f2bfu(v);
    }
    unsigned short* d = (unsigned short*)dst + (size_t)copy * (STREAM_SZ / 2) + (size_t)g * 512;
    *reinterpret_cast<int4*>(d + lane * 8) = u.v;
}

#define MFMA(a, b, c) __builtin_amdgcn_mfma_f32_16x16x32_bf16((a), (b), (c), 0, 0, 0)

// async DMA stage of frag f into the wave's ring slot (f % 140) % 7
#define STAGE(fexpr) do {                                                          \
    const int _f = (fexpr);                                                        \
    const int _fw = (_f >= FRAGS_PER_WAVE) ? (_f - FRAGS_PER_WAVE) : _f;           \
    __builtin_amdgcn_global_load_lds(                                              \
        (const __attribute__((address_space(1))) void*)(stream_lane + (size_t)_fw * 1024), \
        (__attribute__((address_space(3))) void*)(ring_w + (_fw % RING) * 512),    \
        16, 0, 0);                                                                 \
} while (0)

#define SBAR() __builtin_amdgcn_sched_barrier(0)

// keep the newest 5 DMAs in flight
#define WAITV() do {                                   \
    asm volatile("s_waitcnt vmcnt(5)" ::: "memory");   \
    __builtin_amdgcn_sched_barrier(0);                 \
} while (0)

// block barrier WITHOUT vmcnt drain (ring DMAs are wave-private; cross-wave data is DS)
#define BARRIER() asm volatile("s_waitcnt lgkmcnt(0)\n\ts_barrier" ::: "memory")

__global__ __launch_bounds__(THREADS, 4)
void ccnf_main(const float* __restrict__ theta0,
               const float* __restrict__ ctx,
               const float* __restrict__ W1,
               const float* __restrict__ b1,
               const float* __restrict__ b2g,
               const float* __restrict__ b3g,
               const char* __restrict__ wsb,
               const int* __restrict__ nsteps_p,
               float* __restrict__ out, int copyMask)
{
    // LDS: ring 56 KB + hbuf1 4 KB + hbuf2 4 KB + x 256 B + kpart 2 KB ~= 66 KB -> 2 blocks/CU
    __shared__ unsigned short ring[8 * RING * 512];
    __shared__ unsigned short hbuf1[16 * 128];
    __shared__ unsigned short hbuf2[16 * 128];
    __shared__ unsigned short x_lds[128];
    __shared__ float kpart[4 * 128];

    const int tid  = threadIdx.x;
    const int lane = tid & 63;
    const int wv   = tid >> 6;
    const int row0 = blockIdx.x * ROWS;
    const int rowc = lane & 3;             // clamped batch row for B-operand reads
    const int rv   = (lane & 15) < 4;      // valid-row predicate for D-side writes
    const int rb4  = (lane >> 4) * 4;
    const int kgrp = (lane >> 4) * 8;

    const char* stream_lane = wsb + STREAM_OFF
        + (size_t)(blockIdx.x & copyMask) * STREAM_SZ
        + ((size_t)wv * FRAGS_PER_WAVE) * 1024 + lane * 16;
    unsigned short* ring_w = ring + wv * (RING * 512);
    const bf16x8* w1c = reinterpret_cast<const bf16x8*>(wsb + W1C_OFF);

    // ---- prologue: stage ctx into hbuf1 head ([4][136] bf16), theta -> x ----
    unsigned short* ctx_tmp = hbuf1;
    {
        int r = tid >> 7, c = tid & 127;   // 512 floats = 4x128
        ctx_tmp[r * 136 + c] = f2bfu(ctx[(size_t)(row0 + r) * CC + c]);
    }
    float th_reg = 0.f;
    if (tid < ROWS * DD) {
        th_reg = theta0[(size_t)row0 * DD + tid];
        int d = tid & 31, r = tid >> 5;
        x_lds[(d >> 3) * 32 + r * 8 + (d & 7)] = f2bfu(th_reg);
    }
    const int nst = nsteps_p[0];
    const float dt = 1.0f / (float)nst;
    __syncthreads();

    // ---- per-wave register constants: cxt1, w1t, b2 (this wave's 8 ntiles), b3 ----
    u16x4 c1r[4][2], w1tr[4][2], b2r[4][2];
#pragma unroll
    for (int p = 0; p < 4; p++) {
#pragma unroll
        for (int ab = 0; ab < 2; ab++) {
            int nt = wv * 4 + p + 32 * ab;
            f32x4 a = {0.f, 0.f, 0.f, 0.f};
#pragma unroll
            for (int ktc = 0; ktc < 4; ktc++) {
                bf16x8 cf = *reinterpret_cast<const bf16x8*>(&ctx_tmp[rowc * 136 + ktc * 32 + kgrp]);
                a = MFMA(w1c[(nt * 4 + ktc) * 64 + lane], cf, a);
            }
            float4 b1q = *reinterpret_cast<const float4*>(&b1[nt * 16 + rb4]);
            float4 wtq = *reinterpret_cast<const float4*>(&W1[32 * N1 + nt * 16 + rb4]);
            float4 b2q = *reinterpret_cast<const float4*>(&b2g[nt * 16 + rb4]);
            c1r[p][ab][0] = f2bfu(a[0] + b1q.x); c1r[p][ab][1] = f2bfu(a[1] + b1q.y);
            c1r[p][ab][2] = f2bfu(a[2] + b1q.z); c1r[p][ab][3] = f2bfu(a[3] + b1q.w);
            w1tr[p][ab][0] = f2bfu(wtq.x); w1tr[p][ab][1] = f2bfu(wtq.y);
            w1tr[p][ab][2] = f2bfu(wtq.z); w1tr[p][ab][3] = f2bfu(wtq.w);
            b2r[p][ab][0] = f2bfu(b2q.x); b2r[p][ab][1] = f2bfu(b2q.y);
            b2r[p][ab][2] = f2bfu(b2q.z); b2r[p][ab][3] = f2bfu(b2q.w);
        }
    }
    const int nt3 = wv & 1, kq = wv >> 1;
    float4 b3r = *reinterpret_cast<const float4*>(&b3g[nt3 * 16 + rb4]);

    __syncthreads();   // ctx_tmp fully consumed; hbuf1 free for h1; prologue vmem drained

    // ---- warm the ring: frags 0..4 (D=5 outstanding) ----
#pragma unroll
    for (int f = 0; f < 5; f++) STAGE(f);

    // ---- persistent RK4 loop ----
    float acck = 0.f;
    for (int step = 0; step < nst; ++step) {
        float tb = (float)step * dt;
#pragma unroll 1
        for (int s = 0; s < 4; ++s) {
            float tt = tb + ((s == 0) ? 0.f : (s == 3) ? dt : 0.5f * dt);

            // ---- L1: frags 0..7 (B=2/iter), GLU -> hbuf1 ----
            bf16x8 xf = *reinterpret_cast<const bf16x8*>(&x_lds[(lane >> 4) * 32 + rowc * 8]);
#pragma unroll
            for (int p = 0; p < 4; p++) {
                SBAR();
                STAGE(2 * p + 5); STAGE(2 * p + 6);
                WAITV();
                bf16x8 wfA = *reinterpret_cast<const bf16x8*>(ring_w + ((2 * p) % RING) * 512 + lane * 8);
                bf16x8 wfB = *reinterpret_cast<const bf16x8*>(ring_w + ((2 * p + 1) % RING) * 512 + lane * 8);
                f32x4 z = {0.f, 0.f, 0.f, 0.f};
                f32x4 zA = MFMA(wfA, xf, z);
                f32x4 zB = MFMA(wfB, xf, z);
                u16x4 o;
#pragma unroll
                for (int i = 0; i < 4; i++) {
                    float va = zA[i] + bfu2f(c1r[p][0][i]) + tt * bfu2f(w1tr[p][0][i]);
                    float vb = zB[i] + bfu2f(c1r[p][1][i]) + tt * bfu2f(w1tr[p][1][i]);
                    o[i] = f2bfu(va * (1.f / (1.f + __expf(-vb))));
                }
                if (rv) *reinterpret_cast<u16x4*>(&hbuf1[h4_idx(wv * 4 + p, lane)]) = o;
            }
            BARRIER();   // h1 ready

            // ---- L2: frags 8..135, 64 iters of B=2 ----
            f32x4 acc[4][2];
#pragma unroll
            for (int p = 0; p < 4; p++) {
                f32x4 z = {0.f, 0.f, 0.f, 0.f};
                acc[p][0] = z; acc[p][1] = z;
            }
#pragma unroll
            for (int m = 0; m < 64; ++m) {
                const int kt = m >> 2, sub = m & 3;
                SBAR();
                STAGE(2 * m + 13); STAGE(2 * m + 14);
                WAITV();
                bf16x8 hf = *reinterpret_cast<const bf16x8*>(&hbuf1[kt * 128 + (lane >> 4) * 32 + rowc * 8]);
                bf16x8 wf0 = *reinterpret_cast<const bf16x8*>(ring_w + ((8 + 2 * m) % RING) * 512 + lane * 8);
                bf16x8 wf1 = *reinterpret_cast<const bf16x8*>(ring_w + ((9 + 2 * m) % RING) * 512 + lane * 8);
                acc[sub][0] = MFMA(wf0, hf, acc[sub][0]);
                acc[sub][1] = MFMA(wf1, hf, acc[sub][1]);
            }
            // GLU epilogue -> hbuf2
#pragma unroll
            for (int p = 0; p < 4; p++) {
                u16x4 o;
#pragma unroll
                for (int i = 0; i < 4; i++) {
                    float va = acc[p][0][i] + bfu2f(b2r[p][0][i]);
                    float vb = acc[p][1][i] + bfu2f(b2r[p][1][i]);
                    o[i] = f2bfu(va * (1.f / (1.f + __expf(-vb))));
                }
                if (rv) *reinterpret_cast<u16x4*>(&hbuf2[h4_idx(wv * 4 + p, lane)]) = o;
            }
            BARRIER();   // h2 ready

            // ---- L3: frags 136..139 (nt3 = wv&1, kq = wv>>1), 2 iters of B=2 ----
            f32x4 a3 = {0.f, 0.f, 0.f, 0.f};
#pragma unroll
            for (int q2 = 0; q2 < 2; ++q2) {
                SBAR();
                STAGE(141 + 2 * q2); STAGE(142 + 2 * q2);   // next-eval frags 1..4
                WAITV();
#pragma unroll
                for (int j = 0; j < 2; ++j) {
                    int q = q2 * 2 + j;
                    int kt3 = kq * 4 + q;
                    bf16x8 h2f = *reinterpret_cast<const bf16x8*>(&hbuf2[kt3 * 128 + (lane >> 4) * 32 + rowc * 8]);
                    bf16x8 wf = *reinterpret_cast<const bf16x8*>(ring_w + ((136 + q) % RING) * 512 + lane * 8);
                    a3 = MFMA(wf, h2f, a3);
                }
            }
            if (rv) {
                float4 kv4;
                kv4.x = a3[0] + ((kq == 0) ? b3r.x : 0.f);
                kv4.y = a3[1] + ((kq == 0) ? b3r.y : 0.f);
                kv4.z = a3[2] + ((kq == 0) ? b3r.z : 0.f);
                kv4.w = a3[3] + ((kq == 0) ? b3r.w : 0.f);
                *reinterpret_cast<float4*>(&kpart[kq * 128 + (lane & 15) * 32 + nt3 * 16 + rb4]) = kv4;
            }
            // note: frag 140 (next-eval 0) staged at m=63; 141..144 staged above -> 5 in flight
            BARRIER();   // kpart ready

            // ---- RK4 combine (threads 0..127 own element tid: r = tid>>5, d = tid&31) ----
            if (tid < ROWS * DD) {
                float kv = kpart[tid] + kpart[128 + tid] + kpart[256 + tid] + kpart[384 + tid];
                float xe;
                if (s == 0)      { acck = kv;          xe = th_reg + 0.5f * dt * kv; }
                else if (s == 1) { acck += 2.f * kv;   xe = th_reg + 0.5f * dt * kv; }
                else if (s == 2) { acck += 2.f * kv;   xe = th_reg + dt * kv; }
                else             { th_reg += (dt / 6.f) * (acck + kv); xe = th_reg; }
                int d = tid & 31, r = tid >> 5;
                x_lds[(d >> 3) * 32 + r * 8 + (d & 7)] = f2bfu(xe);
            }
            BARRIER();   // x ready; hbuf1/hbuf2/kpart free
        }
    }
    if (tid < ROWS * DD) out[(size_t)row0 * DD + tid] = th_reg;
}

extern "C" void kernel_launch(void* const* d_in, const int* in_sizes, int n_in,
                              void* d_out, int out_size, void* d_ws, size_t ws_size,
                              hipStream_t stream) {
    const float* theta0 = (const float*)d_in[0];
    const float* ctx    = (const float*)d_in[1];
    const float* W1     = (const float*)d_in[2];
    const float* b1     = (const float*)d_in[3];
    const float* W2     = (const float*)d_in[4];
    const float* b2     = (const float*)d_in[5];
    const float* W3     = (const float*)d_in[6];
    const float* b3     = (const float*)d_in[7];
    const int*   nst    = (const int*)d_in[8];
    float* out = (float*)d_out;
    char*  ws  = (char*)d_ws;

    __bf16* w1cp    = (__bf16*)(ws + W1C_OFF);
    __bf16* wstream = (__bf16*)(ws + STREAM_OFF);

    // replicate the stream x8 (one copy per XCD) if workspace allows
    size_t need8 = (size_t)W1C_SZ + 8 * (size_t)STREAM_SZ;
    int ncopy = (ws_size >= need8) ? 8 : 1;
    int copyMask = ncopy - 1;

    pack_kernel<<<256, 64, 0, stream>>>(W1 + 33 * N1, w1cp, CC, N1, 4);
    pack_stream<<<ncopy * 1120, 64, 0, stream>>>(W1, W2, W3, wstream);

    ccnf_main<<<NBLK, THREADS, 0, stream>>>(theta0, ctx, W1, b1, b2, b3,
                                            (const char*)ws, nst, out, copyMask);
}

// Round 6
// 2689.891 us; speedup vs baseline: 2.5044x; 2.5044x over previous
//
#include <hip/hip_runtime.h>
#include <hip/hip_bf16.h>

#define DD 32
#define CC 128
#define N1 1024   // 2*H
#define ROWS 16
#define NBLK 128
#define THREADS 512

#define FRAGS_PER_WAVE 140   // 8 L1 + 128 L2 + 4 L3

typedef float f32x4 __attribute__((ext_vector_type(4)));
typedef __bf16 bf16x8 __attribute__((ext_vector_type(8)));
typedef unsigned short u16x4 __attribute__((ext_vector_type(4)));

#define W1C_OFF 0
#define W1C_SZ (256*1024)
#define STREAM_OFF W1C_SZ
#define STREAM_SZ (1120*1024)   // one copy: 1120 frags x 1 KB

static __device__ __forceinline__ unsigned short f2bfu(float f) {
    __hip_bfloat16 h = __float2bfloat16(f);
    unsigned short u; __builtin_memcpy(&u, &h, 2); return u;
}
static __device__ __forceinline__ float bfu2f(unsigned short u) {
    unsigned int x = ((unsigned int)u) << 16;
    float f; __builtin_memcpy(&f, &x, 4); return f;
}

// fragment-linear LDS index (ushorts) for GLU output write (verified rounds 2/4)
static __device__ __forceinline__ int hw_idx(int nt, int lane) {
    int row = lane & 15, wq = lane >> 4;
    return ((nt >> 1) << 9) + ((((nt << 1) + (wq >> 1)) & 3) * 16 + row) * 8 + (wq & 1) * 4;
}

// old-style pack (used for w1c): frag = nt*4 + kt
__global__ void pack_kernel(const float* __restrict__ W, __bf16* __restrict__ dst,
                            int Kreal, int N, int KT) {
    int frag = blockIdx.x;
    int lane = threadIdx.x;
    int nt = frag / KT, kt = frag - nt * KT;
    int kbase = kt * 32 + (lane >> 4) * 8;
    int n = nt * 16 + (lane & 15);
    union { unsigned short b[8]; int4 v; } u;
#pragma unroll
    for (int j = 0; j < 8; j++) {
        int k = kbase + j;
        float v = (k < Kreal) ? W[(size_t)k * N + n] : 0.f;
        u.b[j] = f2bfu(v);
    }
    *reinterpret_cast<int4*>((unsigned short*)dst + (size_t)frag * 512 + lane * 8) = u.v;
}

// per-wave consumption-order stream pack, replicated ncopy times
__global__ void pack_stream(const float* __restrict__ W1, const float* __restrict__ W2,
                            const float* __restrict__ W3, __bf16* __restrict__ dst) {
    int copy = blockIdx.x / 1120;
    int g = blockIdx.x % 1120;
    int lane = threadIdx.x;
    int wv = g / FRAGS_PER_WAVE, seq = g % FRAGS_PER_WAVE;
    const float* W; int Kreal, N, kt, nt;
    if (seq < 8) {             // L1: theta rows of W1 (K=32)
        int p = seq >> 1, ab = seq & 1;
        W = W1; Kreal = 32; N = N1; kt = 0;
        nt = wv * 4 + p + 32 * ab;
    } else if (seq < 136) {    // L2: kt-major, (p,ab)-minor
        int s = seq - 8;
        int ktt = s >> 3, j = s & 7, p = j >> 1, ab = j & 1;
        W = W2; Kreal = 512; N = N1;
        kt = ktt; nt = wv * 4 + p + 32 * ab;
    } else {                   // L3: wave -> (nt3 = wv&1, kq = wv>>1), kt = kq*4 + q
        int q = seq - 136;
        W = W3; Kreal = 512; N = DD;
        kt = (wv >> 1) * 4 + q; nt = wv & 1;
    }
    int kbase = kt * 32 + (lane >> 4) * 8;
    int n = nt * 16 + (lane & 15);
    union { unsigned short b[8]; int4 v; } u;
#pragma unroll
    for (int j = 0; j < 8; j++) {
        int k = kbase + j;
        float v = (k < Kreal) ? W[(size_t)k * N + n] : 0.f;
        u.b[j] = f2bfu(v);
    }
    unsigned short* d = (unsigned short*)dst + (size_t)copy * (STREAM_SZ / 2) + (size_t)g * 512;
    *reinterpret_cast<int4*>(d + lane * 8) = u.v;
}

#define MFMA(a, b, c) __builtin_amdgcn_mfma_f32_16x16x32_bf16((a), (b), (c), 0, 0, 0)
#define BC(x) __builtin_bit_cast(bf16x8, (x))

// direct global->VGPR load of frag f (compiler cannot sink: explicit asm)
#define LOADG(dst, f) \
    asm volatile("global_load_dwordx4 %0, %1, off" \
                 : "=v"(dst) : "v"(stream_lane + (size_t)(f) * 1024))

// counted waits + scheduler fence (rule 18)
#define W8() do { asm volatile("s_waitcnt vmcnt(8)" ::: "memory"); \
                  __builtin_amdgcn_sched_barrier(0); } while (0)
#define W4() do { asm volatile("s_waitcnt vmcnt(4)" ::: "memory"); \
                  __builtin_amdgcn_sched_barrier(0); } while (0)

// block barrier WITHOUT vmcnt drain (in-flight weight loads survive; cross-wave data is DS)
#define BARRIER() asm volatile("s_waitcnt lgkmcnt(0)\n\ts_barrier" ::: "memory")

__global__ __launch_bounds__(THREADS, 2)
void ccnf_main(const float* __restrict__ theta0,
               const float* __restrict__ ctx,
               const float* __restrict__ W1,
               const float* __restrict__ b1,
               const float* __restrict__ b2g,
               const float* __restrict__ b3g,
               const char* __restrict__ wsb,
               const int* __restrict__ nsteps_p,
               float* __restrict__ out, int copyMask)
{
    // LDS: hbuf1 16 KB + hbuf2 16 KB + x 1 KB + kpart 8 KB = 41 KB
    __shared__ unsigned short hbuf1[16 * 512];
    __shared__ unsigned short hbuf2[16 * 512];
    __shared__ unsigned short x_lds[512];
    __shared__ float kpart[4 * 512];

    const int tid  = threadIdx.x;
    const int lane = tid & 63;
    const int wv   = tid >> 6;
    const int row0 = blockIdx.x * ROWS;
    const int row  = lane & 15;
    const int rb4  = (lane >> 4) * 4;
    const int kgrp = (lane >> 4) * 8;

    const char* stream_lane = wsb + STREAM_OFF
        + (size_t)(blockIdx.x & copyMask) * STREAM_SZ
        + ((size_t)wv * FRAGS_PER_WAVE) * 1024 + lane * 16;
    const bf16x8* w1c = reinterpret_cast<const bf16x8*>(wsb + W1C_OFF);

    // ---- prologue: stage ctx into hbuf1 head ([16][136] bf16) ----
    unsigned short* ctx_tmp = hbuf1;
    {
        int idx = tid * 4;                    // 2048 floats / 512 threads
        int r = idx >> 7, c = idx & 127;
        float4 cv = *reinterpret_cast<const float4*>(&ctx[(size_t)(row0 + r) * CC + c]);
        ctx_tmp[r * 136 + c + 0] = f2bfu(cv.x);
        ctx_tmp[r * 136 + c + 1] = f2bfu(cv.y);
        ctx_tmp[r * 136 + c + 2] = f2bfu(cv.z);
        ctx_tmp[r * 136 + c + 3] = f2bfu(cv.w);
    }
    float th_reg = theta0[(size_t)row0 * DD + tid];
    { int d = tid & 31, r = tid >> 5;
      x_lds[((d >> 3) * 16 + r) * 8 + (d & 7)] = f2bfu(th_reg); }
    const int nst = nsteps_p[0];
    const float dt = 1.0f / (float)nst;
    __syncthreads();

    // ---- per-wave register constants: cxt1, w1t, b2 (this wave's 8 ntiles), b3 ----
    u16x4 c1r[4][2], w1tr[4][2], b2r[4][2];
#pragma unroll
    for (int p = 0; p < 4; p++) {
#pragma unroll
        for (int ab = 0; ab < 2; ab++) {
            int nt = wv * 4 + p + 32 * ab;
            f32x4 a = {0.f, 0.f, 0.f, 0.f};
#pragma unroll
            for (int ktc = 0; ktc < 4; ktc++) {
                bf16x8 cf = *reinterpret_cast<const bf16x8*>(&ctx_tmp[row * 136 + ktc * 32 + kgrp]);
                a = MFMA(w1c[(nt * 4 + ktc) * 64 + lane], cf, a);
            }
            float4 b1q = *reinterpret_cast<const float4*>(&b1[nt * 16 + rb4]);
            float4 wtq = *reinterpret_cast<const float4*>(&W1[32 * N1 + nt * 16 + rb4]);
            float4 b2q = *reinterpret_cast<const float4*>(&b2g[nt * 16 + rb4]);
            c1r[p][ab][0] = f2bfu(a[0] + b1q.x); c1r[p][ab][1] = f2bfu(a[1] + b1q.y);
            c1r[p][ab][2] = f2bfu(a[2] + b1q.z); c1r[p][ab][3] = f2bfu(a[3] + b1q.w);
            w1tr[p][ab][0] = f2bfu(wtq.x); w1tr[p][ab][1] = f2bfu(wtq.y);
            w1tr[p][ab][2] = f2bfu(wtq.z); w1tr[p][ab][3] = f2bfu(wtq.w);
            b2r[p][ab][0] = f2bfu(b2q.x); b2r[p][ab][1] = f2bfu(b2q.y);
            b2r[p][ab][2] = f2bfu(b2q.z); b2r[p][ab][3] = f2bfu(b2q.w);
        }
    }
    const int nt3 = wv & 1, kq = wv >> 1;
    float4 b3r = *reinterpret_cast<const float4*>(&b3g[nt3 * 16 + rb4]);

    __syncthreads();   // ctx_tmp fully consumed; hbuf1 free for h1 (drains prologue vmem too)

    // ---- warm the pipeline: groups G0 (frags 0-3), G1 (frags 4-7) ----
    f32x4 ga[3][4];
    asm volatile("s_waitcnt vmcnt(0)" ::: "memory");
#pragma unroll
    for (int i = 0; i < 4; i++) LOADG(ga[0][i], 0 + i);
#pragma unroll
    for (int i = 0; i < 4; i++) LOADG(ga[1][i], 4 + i);

    // ---- persistent RK4 loop ----
    // Group schedule per eval (35 groups of 4 frags, slots = g%3, lookahead 2):
    //   g=0,1: L1 (consume G0,G1; issue G2,G3)   g=2..33: L2 (consume Gg; issue G(g+2) while g+2<=34)
    //   g=33: W4 (only G33,G34 in flight)        g=34: issue G0', W4, consume G34 (L3), issue G1'
    float acck = 0.f;
    for (int step = 0; step < nst; ++step) {
        float tb = (float)step * dt;
#pragma unroll 1
        for (int s = 0; s < 4; ++s) {
            float tt = tb + ((s == 0) ? 0.f : (s == 3) ? dt : 0.5f * dt);

            // ---- L1: GLU -> hbuf1 ----
            bf16x8 xf = *reinterpret_cast<const bf16x8*>(&x_lds[lane * 8]);
#pragma unroll
            for (int g = 0; g < 2; ++g) {
                const int isl = (g + 2) % 3;
#pragma unroll
                for (int i = 0; i < 4; i++) LOADG(ga[isl][i], 4 * (g + 2) + i);
                W8();
#pragma unroll
                for (int pp = 0; pp < 2; ++pp) {
                    const int p = 2 * g + pp;
                    f32x4 z = {0.f, 0.f, 0.f, 0.f};
                    f32x4 zA = MFMA(BC(ga[g][2 * pp + 0]), xf, z);
                    f32x4 zB = MFMA(BC(ga[g][2 * pp + 1]), xf, z);
                    u16x4 o;
#pragma unroll
                    for (int i = 0; i < 4; i++) {
                        float va = zA[i] + bfu2f(c1r[p][0][i]) + tt * bfu2f(w1tr[p][0][i]);
                        float vb = zB[i] + bfu2f(c1r[p][1][i]) + tt * bfu2f(w1tr[p][1][i]);
                        o[i] = f2bfu(va * (1.f / (1.f + __expf(-vb))));
                    }
                    *reinterpret_cast<u16x4*>(&hbuf1[hw_idx(wv * 4 + p, lane)]) = o;
                }
            }
            BARRIER();   // h1 ready

            // ---- L2: groups G2..G33 (frags 8..135) ----
            f32x4 acc[4][2];
#pragma unroll
            for (int p = 0; p < 4; p++) {
                f32x4 z = {0.f, 0.f, 0.f, 0.f};
                acc[p][0] = z; acc[p][1] = z;
            }
            bf16x8 hf;
#pragma unroll
            for (int j = 0; j < 32; ++j) {
                const int g = 2 + j, sl = g % 3;
                if (j <= 30) {
                    const int isl = (g + 2) % 3;
#pragma unroll
                    for (int i = 0; i < 4; i++) LOADG(ga[isl][i], 4 * (g + 2) + i);
                }
                if (j == 31) { W4(); } else { W8(); }
                const int kt = j >> 1, h = j & 1;
                if (h == 0)
                    hf = *reinterpret_cast<const bf16x8*>(&hbuf1[kt * 512 + lane * 8]);
                acc[2 * h + 0][0] = MFMA(BC(ga[sl][0]), hf, acc[2 * h + 0][0]);
                acc[2 * h + 0][1] = MFMA(BC(ga[sl][1]), hf, acc[2 * h + 0][1]);
                acc[2 * h + 1][0] = MFMA(BC(ga[sl][2]), hf, acc[2 * h + 1][0]);
                acc[2 * h + 1][1] = MFMA(BC(ga[sl][3]), hf, acc[2 * h + 1][1]);
            }
            // GLU epilogue -> hbuf2
#pragma unroll
            for (int p = 0; p < 4; p++) {
                u16x4 o;
#pragma unroll
                for (int i = 0; i < 4; i++) {
                    float va = acc[p][0][i] + bfu2f(b2r[p][0][i]);
                    float vb = acc[p][1][i] + bfu2f(b2r[p][1][i]);
                    o[i] = f2bfu(va * (1.f / (1.f + __expf(-vb))));
                }
                *reinterpret_cast<u16x4*>(&hbuf2[hw_idx(wv * 4 + p, lane)]) = o;
            }
            BARRIER();   // h2 ready

            // ---- L3: group G34 (frags 136-139); pre-issue next eval's G0/G1 ----
#pragma unroll
            for (int i = 0; i < 4; i++) LOADG(ga[0][i], 0 + i);   // G0' -> slot 0
            W4();   // G34 complete (only G34 + G0' were in flight)
            {
                f32x4 a3 = {0.f, 0.f, 0.f, 0.f};
#pragma unroll
                for (int q = 0; q < 4; ++q) {
                    int kt3 = kq * 4 + q;
                    bf16x8 h2f = *reinterpret_cast<const bf16x8*>(&hbuf2[kt3 * 512 + lane * 8]);
                    a3 = MFMA(BC(ga[1][q]), h2f, a3);   // G34 lives in slot 34%3 = 1
                }
                float4 kv4;
                kv4.x = a3[0] + ((kq == 0) ? b3r.x : 0.f);
                kv4.y = a3[1] + ((kq == 0) ? b3r.y : 0.f);
                kv4.z = a3[2] + ((kq == 0) ? b3r.z : 0.f);
                kv4.w = a3[3] + ((kq == 0) ? b3r.w : 0.f);
                *reinterpret_cast<float4*>(&kpart[kq * 512 + row * 32 + nt3 * 16 + rb4]) = kv4;
            }
#pragma unroll
            for (int i = 0; i < 4; i++) LOADG(ga[1][i], 4 + i);   // G1' -> slot 1 (G34 consumed)
            BARRIER();   // kpart ready

            // ---- RK4 combine (thread owns element tid: r = tid>>5, d = tid&31) ----
            {
                float kv = kpart[tid] + kpart[512 + tid] + kpart[1024 + tid] + kpart[1536 + tid];
                float xe;
                if (s == 0)      { acck = kv;          xe = th_reg + 0.5f * dt * kv; }
                else if (s == 1) { acck += 2.f * kv;   xe = th_reg + 0.5f * dt * kv; }
                else if (s == 2) { acck += 2.f * kv;   xe = th_reg + dt * kv; }
                else             { th_reg += (dt / 6.f) * (acck + kv); xe = th_reg; }
                int d = tid & 31, r = tid >> 5;
                x_lds[(d >> 3) * 128 + r * 8 + (d & 7)] = f2bfu(xe);
            }
            BARRIER();   // x ready; hbuf1/hbuf2/kpart free
        }
    }
    out[(size_t)row0 * DD + tid] = th_reg;
}

extern "C" void kernel_launch(void* const* d_in, const int* in_sizes, int n_in,
                              void* d_out, int out_size, void* d_ws, size_t ws_size,
                              hipStream_t stream) {
    const float* theta0 = (const float*)d_in[0];
    const float* ctx    = (const float*)d_in[1];
    const float* W1     = (const float*)d_in[2];
    const float* b1     = (const float*)d_in[3];
    const float* W2     = (const float*)d_in[4];
    const float* b2     = (const float*)d_in[5];
    const float* W3     = (const float*)d_in[6];
    const float* b3     = (const float*)d_in[7];
    const int*   nst    = (const int*)d_in[8];
    float* out = (float*)d_out;
    char*  ws  = (char*)d_ws;

    __bf16* w1cp    = (__bf16*)(ws + W1C_OFF);
    __bf16* wstream = (__bf16*)(ws + STREAM_OFF);

    // 2 stream copies (bounded working set; hedges same-address multicast contention)
    size_t need2 = (size_t)W1C_SZ + 2 * (size_t)STREAM_SZ;
    int ncopy = (ws_size >= need2) ? 2 : 1;
    int copyMask = ncopy - 1;

    pack_kernel<<<256, 64, 0, stream>>>(W1 + 33 * N1, w1cp, CC, N1, 4);
    pack_stream<<<ncopy * 1120, 64, 0, stream>>>(W1, W2, W3, wstream);

    ccnf_main<<<NBLK, THREADS, 0, stream>>>(theta0, ctx, W1, b1, b2, b3,
                                            (const char*)ws, nst, out, copyMask);
}